// Round 1
// baseline (1222.321 us; speedup 1.0000x reference)
//
#include <hip/hip_runtime.h>
#include <hip/hip_bf16.h>
#include <math.h>

// GCN forward: per layer l: hw = (h @ Wl^T) * dinv[row]; h = elu(dinv*(csr_sum hw[src] + hw) + b) + h
// Final: out = sum_l h_l @ lin_w_block_l^T + lin_b  (incremental accumulation, no concat buffer)

__global__ void count_deg_kernel(const int* __restrict__ ei, int E, int* __restrict__ cnt) {
  int stride = gridDim.x * blockDim.x;
  for (int e = blockIdx.x * blockDim.x + threadIdx.x; e < E; e += stride)
    atomicAdd(&cnt[ei[E + e]], 1);
}

__global__ void dinv_kernel(const int* __restrict__ cnt, float* __restrict__ dinv, int n) {
  int stride = gridDim.x * blockDim.x;
  for (int i = blockIdx.x * blockDim.x + threadIdx.x; i < n; i += stride)
    dinv[i] = rsqrtf((float)cnt[i] + 1.0f);  // +1 self-loop
}

// exclusive scan of cnt -> row_ptr (per-1024-chunk partial), bsums[b] = chunk total
__global__ __launch_bounds__(256) void scan1_kernel(const int* __restrict__ cnt,
                                                    int* __restrict__ row_ptr,
                                                    int* __restrict__ bsums, int n) {
  __shared__ int sdata[256];
  int t = threadIdx.x;
  int base = blockIdx.x * 1024;
  int v[4]; int s = 0;
#pragma unroll
  for (int c = 0; c < 4; ++c) {
    int idx = base + t * 4 + c;
    v[c] = (idx < n) ? cnt[idx] : 0;
    s += v[c];
  }
  sdata[t] = s;
  __syncthreads();
  for (int off = 1; off < 256; off <<= 1) {
    int y = (t >= off) ? sdata[t - off] : 0;
    __syncthreads();
    sdata[t] += y;
    __syncthreads();
  }
  int run = sdata[t] - s;  // exclusive prefix of this thread within chunk
#pragma unroll
  for (int c = 0; c < 4; ++c) {
    int idx = base + t * 4 + c;
    if (idx < n) row_ptr[idx] = run;
    run += v[c];
  }
  if (t == 255) bsums[blockIdx.x] = sdata[255];
}

__global__ void scan2_kernel(int* bsums, int nb) {
  if (blockIdx.x == 0 && threadIdx.x == 0) {
    int run = 0;
    for (int i = 0; i < nb; ++i) { int v = bsums[i]; bsums[i] = run; run += v; }
  }
}

__global__ void scan3_kernel(int* __restrict__ row_ptr, const int* __restrict__ bsums,
                             int* __restrict__ pos, int n, int E) {
  int stride = gridDim.x * blockDim.x;
  int gid0 = blockIdx.x * blockDim.x + threadIdx.x;
  for (int i = gid0; i < n; i += stride) {
    int v = row_ptr[i] + bsums[i >> 10];
    row_ptr[i] = v;
    pos[i] = v;
  }
  if (gid0 == 0) row_ptr[n] = E;
}

__global__ void fill_csr_kernel(const int* __restrict__ ei, int E,
                                int* __restrict__ pos, int* __restrict__ col_src) {
  int stride = gridDim.x * blockDim.x;
  for (int e = blockIdx.x * blockDim.x + threadIdx.x; e < E; e += stride) {
    int s = ei[e];
    int d = ei[E + e];
    int p2 = atomicAdd(&pos[d], 1);
    col_src[p2] = s;
  }
}

// C[n x 128] = rs(A[n x 128] @ B^T) (+bias)(+C), B row-major [128 x ldb], K=128
// 64-row tile, 256 threads, per-thread 8 rows x 4 cols; A and B staged k-major in LDS.
__global__ __launch_bounds__(256) void gemm128_kernel(
    const float* __restrict__ A, const float* __restrict__ B, int ldb,
    float* __restrict__ C, const float* __restrict__ row_scale,
    const float* __restrict__ bias, int accum, int n) {
  __shared__ float As[64][64];    // As[k_local][row]
  __shared__ float Bs[64][128];   // Bs[k_local][col]
  int t = threadIdx.x;
  int tx = t & 31;   // col group: 4*tx .. 4*tx+3
  int ty = t >> 5;   // row group: 8*ty .. 8*ty+7
  int row0 = blockIdx.x * 64;
  float acc[8][4] = {{0.f}};
  for (int kh = 0; kh < 2; ++kh) {
    {  // stage A: 64 rows x 64 k (transposed)
      int r = t & 63;
      int q = t >> 6;
      int gr = row0 + r; if (gr >= n) gr = n - 1;
      const float* ap = A + (long)gr * 128 + kh * 64 + q * 16;
#pragma unroll
      for (int c = 0; c < 4; ++c) {
        float4 w = *reinterpret_cast<const float4*>(ap + c * 4);
        int kl = q * 16 + c * 4;
        As[kl + 0][r] = w.x; As[kl + 1][r] = w.y;
        As[kl + 2][r] = w.z; As[kl + 3][r] = w.w;
      }
    }
    {  // stage B: 128 cols x 64 k (transposed)
      int j = t >> 1;
      int ko = (t & 1) * 32;
      const float* bp = B + (long)j * ldb + kh * 64 + ko;
#pragma unroll
      for (int c = 0; c < 8; ++c) {
        float4 w = *reinterpret_cast<const float4*>(bp + c * 4);
        int kl = ko + c * 4;
        Bs[kl + 0][j] = w.x; Bs[kl + 1][j] = w.y;
        Bs[kl + 2][j] = w.z; Bs[kl + 3][j] = w.w;
      }
    }
    __syncthreads();
    for (int k = 0; k < 64; ++k) {
      float a[8], bb[4];
      *reinterpret_cast<float4*>(&a[0]) = *reinterpret_cast<const float4*>(&As[k][ty * 8]);
      *reinterpret_cast<float4*>(&a[4]) = *reinterpret_cast<const float4*>(&As[k][ty * 8 + 4]);
      *reinterpret_cast<float4*>(&bb[0]) = *reinterpret_cast<const float4*>(&Bs[k][tx * 4]);
#pragma unroll
      for (int i = 0; i < 8; ++i)
#pragma unroll
        for (int j2 = 0; j2 < 4; ++j2)
          acc[i][j2] = fmaf(a[i], bb[j2], acc[i][j2]);
    }
    __syncthreads();
  }
  float bv[4] = {0.f, 0.f, 0.f, 0.f};
  if (bias) {
    bv[0] = bias[tx * 4 + 0]; bv[1] = bias[tx * 4 + 1];
    bv[2] = bias[tx * 4 + 2]; bv[3] = bias[tx * 4 + 3];
  }
#pragma unroll
  for (int i = 0; i < 8; ++i) {
    int gr = row0 + ty * 8 + i;
    if (gr < n) {
      float rs = row_scale ? row_scale[gr] : 1.0f;
      float* cp = C + (long)gr * 128 + tx * 4;
      float4 o;
      o.x = acc[i][0] * rs + bv[0];
      o.y = acc[i][1] * rs + bv[1];
      o.z = acc[i][2] * rs + bv[2];
      o.w = acc[i][3] * rs + bv[3];
      if (accum) {
        float4 old = *reinterpret_cast<const float4*>(cp);
        o.x += old.x; o.y += old.y; o.z += old.z; o.w += old.w;
      }
      *reinterpret_cast<float4*>(cp) = o;
    }
  }
}

// one block (128 threads) per node: segment-sum of hw rows + self-loop, then
// h[i] = elu(dinv[i]*acc + bias) + h[i]   (in place)
__global__ __launch_bounds__(128) void aggregate_kernel(
    const float* __restrict__ hw, const int* __restrict__ col_src,
    const int* __restrict__ row_ptr, const float* __restrict__ dinv,
    const float* __restrict__ bias, float* __restrict__ h, int n) {
  int i = blockIdx.x;
  int d = threadIdx.x;
  float acc = hw[(long)i * 128 + d];  // self-loop term (hw already dinv[row]-scaled)
  int e0 = row_ptr[i], e1 = row_ptr[i + 1];
  for (int e = e0; e < e1; ++e) {
    int s = col_src[e];
    acc += hw[(long)s * 128 + d];
  }
  float x = fmaf(acc, dinv[i], bias[d]);
  float v = (x > 0.f) ? x : expm1f(x);
  h[(long)i * 128 + d] += v;
}

extern "C" void kernel_launch(void* const* d_in, const int* in_sizes, int n_in,
                              void* d_out, int out_size, void* d_ws, size_t ws_size,
                              hipStream_t stream) {
  const float* x      = (const float*)d_in[0];
  const int*   ei     = (const int*)d_in[1];
  const float* conv_w = (const float*)d_in[2];
  const float* conv_b = (const float*)d_in[3];
  const float* lin_w  = (const float*)d_in[4];
  const float* lin_b  = (const float*)d_in[5];
  float* out = (float*)d_out;

  const int n = in_sizes[0] / 128;
  const int E = in_sizes[1] / 2;
  const int L = in_sizes[2] / (128 * 128);
  const int nb = (n + 1023) / 1024;

  char* p = (char*)d_ws;
  auto carve = [&](size_t bytes) {
    char* r = p;
    p += (bytes + 255) & ~(size_t)255;
    return r;
  };
  int*   cnt     = (int*)carve((size_t)n * 4);
  int*   row_ptr = (int*)carve((size_t)(n + 1) * 4);
  int*   pos     = (int*)carve((size_t)n * 4);
  int*   bsums   = (int*)carve((size_t)nb * 4);
  int*   col_src = (int*)carve((size_t)E * 4);
  float* dinv    = (float*)carve((size_t)n * 4);
  float* h       = (float*)carve((size_t)n * 128 * 4);
  float* hw      = (float*)carve((size_t)n * 128 * 4);

  // --- degree + CSR build (reused across all 3 layers) ---
  hipMemsetAsync(cnt, 0, (size_t)n * 4, stream);
  count_deg_kernel<<<2048, 256, 0, stream>>>(ei, E, cnt);
  dinv_kernel<<<(n + 255) / 256, 256, 0, stream>>>(cnt, dinv, n);
  scan1_kernel<<<nb, 256, 0, stream>>>(cnt, row_ptr, bsums, n);
  scan2_kernel<<<1, 64, 0, stream>>>(bsums, nb);
  scan3_kernel<<<(n + 255) / 256, 256, 0, stream>>>(row_ptr, bsums, pos, n, E);
  fill_csr_kernel<<<2048, 256, 0, stream>>>(ei, E, pos, col_src);

  // h = x
  hipMemcpyAsync(h, x, (size_t)n * 128 * 4, hipMemcpyDeviceToDevice, stream);

  int gblocks = (n + 63) / 64;
  // out = x @ lin_w_block0^T + lin_b
  gemm128_kernel<<<gblocks, 256, 0, stream>>>(x, lin_w, 512, out, nullptr, lin_b, 0, n);
  for (int l = 0; l < L; ++l) {
    // hw = (h @ Wl^T) * dinv[row]
    gemm128_kernel<<<gblocks, 256, 0, stream>>>(h, conv_w + (size_t)l * 128 * 128, 128,
                                                hw, dinv, nullptr, 0, n);
    // h = elu(dinv*(sum_in hw + hw_self) + b) + h
    aggregate_kernel<<<n, 128, 0, stream>>>(hw, col_src, row_ptr, dinv,
                                            conv_b + (size_t)l * 128, h, n);
    // out += h @ lin_w_block_{l+1}^T
    gemm128_kernel<<<gblocks, 256, 0, stream>>>(h, lin_w + (size_t)(l + 1) * 128, 512,
                                                out, nullptr, nullptr, 1, n);
  }
}